// Round 10
// baseline (48.572 us; speedup 1.0000x reference)
//
#include <hip/hip_runtime.h>

#define HH 160
#define WW 160
#define CC 32
#define NN 8
#define PIX (HH * WW)   // 25600

typedef float f32x2 __attribute__((ext_vector_type(2)));
typedef float f32x4 __attribute__((ext_vector_type(4)));

// Block: 640 threads = 4 cg x 2 halves x 80 w-pairs (one FULL feature row
// per block -> R6's proven write coherence). Each thread: 8 channels, pixel
// pair (2p,2p+1), ONE output row (2h+half) -> one f32x4 store per channel.
// NO LDS: the 18 per-thread kernel taps are loaded straight from global as
// coalesced f32x2 (lanes stride 8B). This removes R8's failure mode (compiler
// rematerializing kv from LDS each channel) and cuts VMEM insts/output to
// ~3 (vs R6's ~4.25) to attack the VMEM-issue co-bottleneck.
__global__ __launch_bounds__(640, 6) void pixelconv_k(
    const float* __restrict__ feature,   // [8,32,160,160]
    const float* __restrict__ kern,      // [8,36,160,160]
    float* __restrict__ out)             // [8,32,320,320]
{
    const int bx = blockIdx.x;                 // 0..159
    const int h  = (bx & 7) * 20 + (bx >> 3);  // XCD-chunked h swizzle
    const int n  = blockIdx.y;                 // 0..7
    const int t  = threadIdx.x;                // 0..639
    const int p    = t % 80;                   // w-pair (w0 = 2p)
    const int half = (t / 80) & 1;             // 0: out row 2h, 1: row 2h+1
    const int cg   = t / 160;                  // 0..3 (8 channels each)
    const int w0 = 2 * p;

    // kv direct from global: j = 4k + 2*half + r2, value pair (w0, w0+1).
    // kvA[k]: r2=0, kvA[k].x -> pixel w0, .y -> pixel w0+1 ; kvB[k]: r2=1.
    const float* kb = kern + ((size_t)n * 36 + 2 * half) * PIX
                           + (size_t)h * WW + w0;
    f32x2 kvA[9], kvB[9];
    #pragma unroll
    for (int k = 0; k < 9; ++k) {
        kvA[k] = *(const f32x2*)(kb + (size_t)(4 * k) * PIX);
        kvB[k] = *(const f32x2*)(kb + (size_t)(4 * k + 1) * PIX);
    }

    const bool hm = (h > 0), hp = (h < HH - 1);
    const bool wm = (p > 0), wp = (p < 79);

    const float* fc = feature + ((size_t)(n * CC + cg * 8)) * PIX
                              + (size_t)h * WW + w0;
    float* oc = out + ((size_t)(n * CC + cg * 8)) * 4 * PIX
                    + (size_t)(2 * h + half) * (2 * WW) + 4 * p;

    #pragma unroll 2
    for (int i = 0; i < 8; ++i) {
        // rows h-1..h+1, cols w0-1..w0+2 -> r[3][4] (f32x2 mid + 2 scalars)
        float r[3][4];
        #pragma unroll
        for (int dy = 0; dy < 3; ++dy) {
            const bool okh = (dy == 1) || (dy == 0 ? hm : hp);
            const float* rowp = fc + (dy - 1) * WW;
            f32x2 mid = okh ? *(const f32x2*)rowp : (f32x2){0.f, 0.f};
            r[dy][1] = mid.x;
            r[dy][2] = mid.y;
            r[dy][0] = (okh && wm) ? rowp[-1] : 0.f;
            r[dy][3] = (okh && wp) ? rowp[2]  : 0.f;
        }

        // outputs: (px0,r2=0), (px0,r2=1), (px1,r2=0), (px1,r2=1)
        float a00 = 0.f, a01 = 0.f, a10 = 0.f, a11 = 0.f;
        #pragma unroll
        for (int dx = 0; dx < 3; ++dx) {
            #pragma unroll
            for (int dy = 0; dy < 3; ++dy) {
                const int k = dx * 3 + dy;
                const float f0 = r[dy][dx];      // px0 tap
                const float f1 = r[dy][dx + 1];  // px1 tap
                a00 = fmaf(f0, kvA[k].x, a00);
                a01 = fmaf(f0, kvB[k].x, a01);
                a10 = fmaf(f1, kvA[k].y, a10);
                a11 = fmaf(f1, kvB[k].y, a11);
            }
        }

        // contiguous f32x4 of output row (2h+half), cols 4p..4p+3
        *(f32x4*)oc = (f32x4){a00, a01, a10, a11};

        fc += PIX;               // next channel's feature plane
        oc += (size_t)4 * PIX;   // next channel's output plane
    }
}

extern "C" void kernel_launch(void* const* d_in, const int* in_sizes, int n_in,
                              void* d_out, int out_size, void* d_ws, size_t ws_size,
                              hipStream_t stream) {
    const float* feature = (const float*)d_in[0];
    const float* kern    = (const float*)d_in[1];
    float* out           = (float*)d_out;

    dim3 grid(HH, NN, 1);   // (160, 8)
    pixelconv_k<<<grid, 640, 0, stream>>>(feature, kern, out);
}

// Round 11
// 47.601 us; speedup vs baseline: 1.0204x; 1.0204x over previous
//
#include <hip/hip_runtime.h>

#define HH 160
#define WW 160
#define CC 32
#define NN 8
#define PIX (HH * WW)   // 25600

typedef float f32x2 __attribute__((ext_vector_type(2)));
typedef float f32x4 __attribute__((ext_vector_type(4)));

// Block: 640 threads = 4 cg x 2 halves x 80 w-pairs (full row h per block ->
// R6's proven write-coherent structure, XCD-swizzled h). Each thread: 8
// channels of a pixel pair, one output row (2h+half) -> one f32x4 store per
// channel. The 36 kv floats are PINNED in VGPRs via identity asm after the
// LDS read: R7/R8/R9 all died because the allocator spilled or rematerialized
// kv on the dependent path; the pin makes the value opaque so it must stay
// resident. No restrictive launch_bounds (natural ~90 VGPR -> 2 blocks/CU).
__global__ __launch_bounds__(640) void pixelconv_k(
    const float* __restrict__ feature,   // [8,32,160,160]
    const float* __restrict__ kern,      // [8,36,160,160]
    float* __restrict__ out)             // [8,32,320,320]
{
    const int bx = blockIdx.x;                 // 0..159
    const int h  = (bx & 7) * 20 + (bx >> 3);  // XCD-chunked h swizzle
    const int n  = blockIdx.y;                 // 0..7
    const int t  = threadIdx.x;                // 0..639
    const int p    = t % 80;                   // w-pair (w0 = 2p)
    const int half = (t / 80) & 1;             // 0: out row 2h, 1: row 2h+1
    const int cg   = t / 160;                  // 0..3 (8 channels each)
    const int w0 = 2 * p;

    // ---- stage kernel[n][0:36][h][0:160] into LDS ----
    __shared__ float kv_lds[36 * 160];
    const float* kbase = kern + (size_t)n * 36 * PIX + (size_t)h * WW;
    #pragma unroll
    for (int r = 0; r < 9; ++r) {
        const int idx = t + r * 640;           // 5760 = 9 * 640 exactly
        const int j   = idx / 160;
        const int ws  = idx - j * 160;
        kv_lds[idx] = kbase[(size_t)j * PIX + ws];
    }
    __syncthreads();

    // kv for this thread: j = 4k + 2*half + r2, pixels (w0, w0+1).
    // kA*: r2=0 (even out col), kB*: r2=1 (odd). Suffix 0/1 = pixel w0/w0+1.
    // Pinned via identity asm so the allocator can neither spill nor
    // rematerialize them inside the channel loop.
    float kA0[9], kA1[9], kB0[9], kB1[9];
    #pragma unroll
    for (int k = 0; k < 9; ++k) {
        f32x2 tA = *(const f32x2*)&kv_lds[(4 * k + 2 * half)     * 160 + w0];
        f32x2 tB = *(const f32x2*)&kv_lds[(4 * k + 2 * half + 1) * 160 + w0];
        kA0[k] = tA.x; kA1[k] = tA.y;
        kB0[k] = tB.x; kB1[k] = tB.y;
        asm volatile("" : "+v"(kA0[k]), "+v"(kA1[k]), "+v"(kB0[k]), "+v"(kB1[k]));
    }

    const bool hm = (h > 0), hp = (h < HH - 1);
    const bool wm = (p > 0), wp = (p < 79);

    const float* fc = feature + ((size_t)(n * CC + cg * 8)) * PIX
                              + (size_t)h * WW + w0;
    float* oc = out + ((size_t)(n * CC + cg * 8)) * 4 * PIX
                    + (size_t)(2 * h + half) * (2 * WW) + 4 * p;

    #pragma unroll 2
    for (int i = 0; i < 8; ++i) {
        // rows h-1..h+1, cols w0-1..w0+2 -> r[3][4] (f32x2 mid + 2 scalars)
        float r[3][4];
        #pragma unroll
        for (int dy = 0; dy < 3; ++dy) {
            const bool okh = (dy == 1) || (dy == 0 ? hm : hp);
            const float* rowp = fc + (dy - 1) * WW;
            f32x2 mid = okh ? *(const f32x2*)rowp : (f32x2){0.f, 0.f};
            r[dy][1] = mid.x;
            r[dy][2] = mid.y;
            r[dy][0] = (okh && wm) ? rowp[-1] : 0.f;
            r[dy][3] = (okh && wp) ? rowp[2]  : 0.f;
        }

        // outputs: (px0,r2=0), (px0,r2=1), (px1,r2=0), (px1,r2=1)
        float a00 = 0.f, a01 = 0.f, a10 = 0.f, a11 = 0.f;
        #pragma unroll
        for (int dx = 0; dx < 3; ++dx) {
            #pragma unroll
            for (int dy = 0; dy < 3; ++dy) {
                const int k = dx * 3 + dy;
                a00 = fmaf(r[dy][dx],     kA0[k], a00);
                a01 = fmaf(r[dy][dx],     kB0[k], a01);
                a10 = fmaf(r[dy][dx + 1], kA1[k], a10);
                a11 = fmaf(r[dy][dx + 1], kB1[k], a11);
            }
        }

        // contiguous f32x4 of output row (2h+half), cols 4p..4p+3
        *(f32x4*)oc = (f32x4){a00, a01, a10, a11};

        fc += PIX;               // next channel's feature plane
        oc += (size_t)4 * PIX;   // next channel's output plane
    }
}

extern "C" void kernel_launch(void* const* d_in, const int* in_sizes, int n_in,
                              void* d_out, int out_size, void* d_ws, size_t ws_size,
                              hipStream_t stream) {
    const float* feature = (const float*)d_in[0];
    const float* kern    = (const float*)d_in[1];
    float* out           = (float*)d_out;

    dim3 grid(HH, NN, 1);   // (160, 8)
    pixelconv_k<<<grid, 640, 0, stream>>>(feature, kern, out);
}